// Round 1
// baseline (551.902 us; speedup 1.0000x reference)
//
#include <hip/hip_runtime.h>

#define DD 160
#define HH 160
#define WW 160
#define NVOX (DD * HH * WW)

// v0 = velocity * s  (vectorized float4 elementwise)
__global__ __launch_bounds__(256) void gs_init_scale(const float* __restrict__ in,
                                                     float* __restrict__ out,
                                                     int n4, float s) {
    int i = blockIdx.x * blockDim.x + threadIdx.x;
    if (i < n4) {
        float4 v = reinterpret_cast<const float4*>(in)[i];
        v.x *= s; v.y *= s; v.z *= s; v.w *= s;
        reinterpret_cast<float4*>(out)[i] = v;
    }
}

// One step: vout = vin + trilinear_sample(vin, grid + vin)
// vol layout: [D, H, W, 3] channels-last, align_corners=true, zeros padding.
__global__ __launch_bounds__(256) void gs_step(const float* __restrict__ vin,
                                               const float* __restrict__ grid,
                                               float* __restrict__ vout) {
    int tid = blockIdx.x * blockDim.x + threadIdx.x;
    if (tid >= NVOX) return;

    int base = tid * 3;
    float vx = vin[base + 0];
    float vy = vin[base + 1];
    float vz = vin[base + 2];

    float cx = grid[base + 0] + vx;
    float cy = grid[base + 1] + vy;
    float cz = grid[base + 2] + vz;

    // normalized -> pixel coords (align_corners=true)
    float fx = (cx + 1.0f) * 0.5f * (float)(WW - 1);
    float fy = (cy + 1.0f) * 0.5f * (float)(HH - 1);
    float fz = (cz + 1.0f) * 0.5f * (float)(DD - 1);

    float x0f = floorf(fx), y0f = floorf(fy), z0f = floorf(fz);
    float wx = fx - x0f, wy = fy - y0f, wz = fz - z0f;
    int x0 = (int)x0f, y0 = (int)y0f, z0 = (int)z0f;

    float acc0 = 0.0f, acc1 = 0.0f, acc2 = 0.0f;

#pragma unroll
    for (int dz = 0; dz < 2; ++dz) {
        int zi = z0 + dz;
        float wzz = dz ? wz : (1.0f - wz);
        bool zok = (zi >= 0) & (zi < DD);
#pragma unroll
        for (int dy = 0; dy < 2; ++dy) {
            int yi = y0 + dy;
            float wyy = dy ? wy : (1.0f - wy);
            bool yok = (yi >= 0) & (yi < HH);
#pragma unroll
            for (int dx = 0; dx < 2; ++dx) {
                int xi = x0 + dx;
                float wxx = dx ? wx : (1.0f - wx);
                bool xok = (xi >= 0) & (xi < WW);
                if (zok & yok & xok) {
                    const float* p = vin + ((size_t)(zi * HH + yi) * WW + xi) * 3;
                    float w = wzz * wyy * wxx;
                    acc0 += w * p[0];
                    acc1 += w * p[1];
                    acc2 += w * p[2];
                }
            }
        }
    }

    vout[base + 0] = vx + acc0;
    vout[base + 1] = vy + acc1;
    vout[base + 2] = vz + acc2;
}

extern "C" void kernel_launch(void* const* d_in, const int* in_sizes, int n_in,
                              void* d_out, int out_size, void* d_ws, size_t ws_size,
                              hipStream_t stream) {
    const float* vel  = (const float*)d_in[0];
    const float* grid = (const float*)d_in[1];
    float* out = (float*)d_out;   // buffer A
    float* ws  = (float*)d_ws;    // buffer B

    const int n_elem = NVOX * 3;          // 12,288,000
    const int n4 = n_elem / 4;            // float4 count
    const float scale = 1.0f / 64.0f;     // 1 / 2^n, n = 6

    dim3 blk(256);
    dim3 grd_init((n4 + 255) / 256);
    dim3 grd_step((NVOX + 255) / 256);

    // init: v0 into d_out
    gs_init_scale<<<grd_init, blk, 0, stream>>>(vel, out, n4, scale);

    // 6 steps, ping-pong: out->ws, ws->out, ... ends in out (even count)
    float* src = out;
    float* dst = ws;
    for (int i = 0; i < 6; ++i) {
        gs_step<<<grd_step, blk, 0, stream>>>(src, grid, dst);
        float* t = src; src = dst; dst = t;
    }
    // after 6 steps, result is in `out` (== d_out)
}